// Round 1
// baseline (176.509 us; speedup 1.0000x reference)
//
#include <hip/hip_runtime.h>
#include <math.h>

// MultiEmbeddingSGNS: out[b] = sigmoid( dot( sum_i wt_i*T_i[x[b,i]],
//                                            sum_i wc_i*C_i[x[b,i]] ) )
// wt = softmax(tgt_w), wc = softmax(ctx_w), D=128, BS=16384.
//
// One wave (64 lanes) per batch element, HALF-WAVE SPLIT:
//   lanes 0-31  : target tables, lane covers dims {4c..4c+3} via float4
//   lanes 32-63 : context tables, same dims
// Each lane does 3 x global_load_dwordx4 (16 B/lane = 1 KiB/instr, the
// coalescing sweet spot) instead of 6 x dwordx2. The t.c dot crosses the
// halves with 4 __shfl_down(..,32), then a 5-step half-wave reduce.

#define D 128
#define WAVES_PER_BLOCK 4

__global__ __launch_bounds__(64 * WAVES_PER_BLOCK)
void sgns_kernel(const int* __restrict__ x,
                 const float* __restrict__ tgt_base,
                 const float* __restrict__ tgt_a,
                 const float* __restrict__ tgt_b,
                 const float* __restrict__ ctx_base,
                 const float* __restrict__ ctx_a,
                 const float* __restrict__ ctx_b,
                 const float* __restrict__ tgt_w,
                 const float* __restrict__ ctx_w,
                 float* __restrict__ out,
                 int bs) {
    const int wave = threadIdx.x >> 6;
    const int lane = threadIdx.x & 63;
    const int b = blockIdx.x * WAVES_PER_BLOCK + wave;
    if (b >= bs) return;

    const int half = lane >> 5;   // 0 = target half, 1 = context half
    const int col  = lane & 31;   // float4 column within the D=128 row

    // Each half computes only its own 3-way softmax.
    const float* __restrict__ wsrc = half ? ctx_w : tgt_w;
    float w0 = wsrc[0], w1 = wsrc[1], w2 = wsrc[2];
    const float m = fmaxf(w0, fmaxf(w1, w2));
    const float e0 = __expf(w0 - m), e1 = __expf(w1 - m), e2 = __expf(w2 - m);
    const float inv = 1.0f / (e0 + e1 + e2);
    w0 = e0 * inv; w1 = e1 * inv; w2 = e2 * inv;

    // Indices (wave-uniform broadcast loads).
    const int i0 = x[b * 3 + 0];
    const int i1 = x[b * 3 + 1];
    const int i2 = x[b * 3 + 2];

    // Per-half table bases.
    const float* __restrict__ t0 = half ? ctx_base : tgt_base;
    const float* __restrict__ t1 = half ? ctx_a    : tgt_a;
    const float* __restrict__ t2 = half ? ctx_b    : tgt_b;

    // 3 independent 16B loads per lane: 32 lanes * 16 B = one full row.
    const float4 ra = ((const float4*)(t0 + (size_t)i0 * D))[col];
    const float4 rb = ((const float4*)(t1 + (size_t)i1 * D))[col];
    const float4 rc = ((const float4*)(t2 + (size_t)i2 * D))[col];

    // Weighted embedding for this half's 4 dims.
    const float vx = w0 * ra.x + w1 * rb.x + w2 * rc.x;
    const float vy = w0 * ra.y + w1 * rb.y + w2 * rc.y;
    const float vz = w0 * ra.z + w1 * rb.z + w2 * rc.z;
    const float vw = w0 * ra.w + w1 * rb.w + w2 * rc.w;

    // Pull the context half's values down to lanes 0..31.
    const float ox = __shfl_down(vx, 32, 64);
    const float oy = __shfl_down(vy, 32, 64);
    const float oz = __shfl_down(vz, 32, 64);
    const float ow = __shfl_down(vw, 32, 64);

    // Partial dot: valid in lanes 0..31 only.
    float p = vx * ox + vy * oy + vz * oz + vw * ow;

    // Half-wave reduction over lanes 0..31.
    #pragma unroll
    for (int off = 16; off > 0; off >>= 1)
        p += __shfl_down(p, off, 64);

    if (lane == 0)
        out[b] = 1.0f / (1.0f + __expf(-p));
}

extern "C" void kernel_launch(void* const* d_in, const int* in_sizes, int n_in,
                              void* d_out, int out_size, void* d_ws, size_t ws_size,
                              hipStream_t stream) {
    const int*   x        = (const int*)  d_in[0];
    const float* tgt_base = (const float*)d_in[1];
    const float* tgt_a    = (const float*)d_in[2];
    const float* tgt_b    = (const float*)d_in[3];
    const float* ctx_base = (const float*)d_in[4];
    const float* ctx_a    = (const float*)d_in[5];
    const float* ctx_b    = (const float*)d_in[6];
    const float* tgt_w    = (const float*)d_in[7];
    const float* ctx_w    = (const float*)d_in[8];
    float* out = (float*)d_out;

    const int bs = out_size;  // 16384
    const int block = 64 * WAVES_PER_BLOCK;
    const int grid = (bs + WAVES_PER_BLOCK - 1) / WAVES_PER_BLOCK;

    sgns_kernel<<<grid, block, 0, stream>>>(x, tgt_base, tgt_a, tgt_b,
                                            ctx_base, ctx_a, ctx_b,
                                            tgt_w, ctx_w, out, bs);
}